// Round 11
// baseline (1018.885 us; speedup 1.0000x reference)
//
#include <hip/hip_runtime.h>

#define C 16
#define TAPS 27
#define NCONV 17
#define LISTCAP 98304   // >> expected ~88.5K actives

// tap -> (kz,ky,kx) lookup (avoids div/mod on the critical path)
__device__ __constant__ int cKZ[TAPS] = {0,0,0,0,0,0,0,0,0, 1,1,1,1,1,1,1,1,1, 2,2,2,2,2,2,2,2,2};
__device__ __constant__ int cKY[TAPS] = {0,0,0,1,1,1,2,2,2, 0,0,0,1,1,1,2,2,2, 0,0,0,1,1,1,2,2,2};
__device__ __constant__ int cKX[TAPS] = {0,1,2,0,1,2,0,1,2, 0,1,2,0,1,2,0,1,2, 0,1,2,0,1,2,0,1,2};

// ---- weight prep: W[l][co][ci][tap] -> Wq[l][cq][tap][ci][4]  (co = cq*4+j) ----
__global__ void wq_kernel(const float* __restrict__ W, float* __restrict__ Wq) {
    int i = blockIdx.x * blockDim.x + threadIdx.x;
    const int total = NCONV * 4 * TAPS * C * 4;
    if (i >= total) return;
    int j = i & 3;
    int ci = (i >> 2) & 15;
    int t = (i >> 6) % TAPS;
    int rest = (i >> 6) / TAPS;
    int cq = rest & 3;
    int l = rest >> 2;
    int co = cq * 4 + j;
    Wq[i] = W[(((l * C + co) * C + ci) * TAPS) + t];
}

// ---- x: NCDHW -> NDHWC ----
__global__ void transpose_in_kernel(const float* __restrict__ x, float* __restrict__ xt, int n) {
    int v = blockIdx.x * blockDim.x + threadIdx.x;
    if (v >= n) return;
    float a[C];
#pragma unroll
    for (int ci = 0; ci < C; ci++) a[ci] = x[(long)ci * n + v];
    float4* dp = reinterpret_cast<float4*>(xt + (long)v * C);
    dp[0] = make_float4(a[0], a[1], a[2], a[3]);
    dp[1] = make_float4(a[4], a[5], a[6], a[7]);
    dp[2] = make_float4(a[8], a[9], a[10], a[11]);
    dp[3] = make_float4(a[12], a[13], a[14], a[15]);
}

// ---- NDHWC -> NCDHW (stage outputs into d_out) ----
__global__ void to_ncdhw_kernel(const float* __restrict__ src, float* __restrict__ dst, int n) {
    int v = blockIdx.x * blockDim.x + threadIdx.x;
    if (v >= n) return;
    const float4* sp = reinterpret_cast<const float4*>(src + (long)v * C);
    float4 q0 = sp[0], q1 = sp[1], q2 = sp[2], q3 = sp[3];
    dst[0L * n + v] = q0.x;  dst[1L * n + v] = q0.y;
    dst[2L * n + v] = q0.z;  dst[3L * n + v] = q0.w;
    dst[4L * n + v] = q1.x;  dst[5L * n + v] = q1.y;
    dst[6L * n + v] = q1.z;  dst[7L * n + v] = q1.w;
    dst[8L * n + v] = q2.x;  dst[9L * n + v] = q2.y;
    dst[10L * n + v] = q2.z; dst[11L * n + v] = q2.w;
    dst[12L * n + v] = q3.x; dst[13L * n + v] = q3.y;
    dst[14L * n + v] = q3.z; dst[15L * n + v] = q3.w;
}

// ---- ordered compaction: counts -> scan -> scatter ----
__global__ void count_kernel(const int* __restrict__ mi, int* __restrict__ counts, int n) {
    int i = blockIdx.x * 256 + threadIdx.x;
    int act = (i < n) && (mi[i] == 0);
    unsigned long long b = __ballot(act);
    __shared__ int wsum[4];
    int wid = threadIdx.x >> 6, lane = threadIdx.x & 63;
    if (lane == 0) wsum[wid] = __popcll(b);
    __syncthreads();
    if (threadIdx.x == 0) counts[blockIdx.x] = wsum[0] + wsum[1] + wsum[2] + wsum[3];
}

__global__ void scan_kernel(const int* __restrict__ counts, int* __restrict__ offsets,
                            int* __restrict__ nact, int nb) {
    __shared__ int s[256];
    int t = threadIdx.x;
    const int CH = (nb + 255) / 256;
    int base = t * CH, sum = 0;
    for (int j = 0; j < CH; j++)
        if (base + j < nb) sum += counts[base + j];
    s[t] = sum;
    __syncthreads();
    for (int off = 1; off < 256; off <<= 1) {
        int v = (t >= off) ? s[t - off] : 0;
        __syncthreads();
        s[t] += v;
        __syncthreads();
    }
    int run = s[t] - sum;  // exclusive base
    for (int j = 0; j < CH; j++) {
        if (base + j < nb) {
            offsets[base + j] = run;
            run += counts[base + j];
        }
    }
    if (t == 255) *nact = s[255];
}

__global__ void scatter_kernel(const int* __restrict__ mi, const int* __restrict__ offsets,
                               int* __restrict__ list, int n, int cap) {
    int i = blockIdx.x * 256 + threadIdx.x;
    int act = (i < n) && (mi[i] == 0);
    unsigned long long b = __ballot(act);
    __shared__ int wsum[4];
    int wid = threadIdx.x >> 6, lane = threadIdx.x & 63;
    if (lane == 0) wsum[wid] = __popcll(b);
    __syncthreads();
    int wbase = 0;
    for (int w = 0; w < wid; w++) wbase += wsum[w];
    int prefix = __popcll(b & ((1ull << lane) - 1));
    if (act) {
        int pos = offsets[blockIdx.x] + wbase + prefix;
        if (pos < cap) list[pos] = i;
    }
}

// ---- mask maxpool (2x2x2 stride, 3^3 window) ----
template <bool FROM_INT>
__global__ void pool_mask_kernel(const int* __restrict__ mi, const float* __restrict__ mf,
                                 float* __restrict__ mout, int Din, int Dout) {
    int i = blockIdx.x * blockDim.x + threadIdx.x;
    int n = Dout * Dout * Dout;
    if (i >= n) return;
    int x = i % Dout, y = (i / Dout) % Dout, z = i / (Dout * Dout);
    float v = 0.f;
    for (int kz = 0; kz < 3; kz++) {
        int zz = 2 * z - 1 + kz;
        if (zz < 0 || zz >= Din) continue;
        for (int ky = 0; ky < 3; ky++) {
            int yy = 2 * y - 1 + ky;
            if (yy < 0 || yy >= Din) continue;
            for (int kx = 0; kx < 3; kx++) {
                int xx = 2 * x - 1 + kx;
                if (xx < 0 || xx >= Din) continue;
                long idx = ((long)zz * Din + yy) * Din + xx;
                float mv = FROM_INT ? ((mi[idx] == 0) ? 1.f : 0.f) : mf[idx];
                v = fmaxf(v, mv);
            }
        }
    }
    mout[i] = v;
}

// ---- conv in NDHWC: block = 128 voxels x 4 co-quad waves (256 thr) ----
// Thread: V=2 voxels x Q=4 co, all 16 ci. Weights on the SCALAR path:
// address chain rooted at readfirstlane(cq) -> s_load of 64 contiguous floats
// per tap (sK$-hot after first pass); v_fmac takes the SGPR operand directly.
// Inputs: 8 float4/tap/thread, 2-deep tap prefetch (16 quads, no spill).
// No LDS, no weight VMEM, no div/mod in the tap loop (constant LUTs).
#define CIW(AQ, BQ, CMP, CI)                                        \
    {                                                               \
        float w0_ = wt_[(CI) * 4 + 0], w1_ = wt_[(CI) * 4 + 1];     \
        float w2_ = wt_[(CI) * 4 + 2], w3_ = wt_[(CI) * 4 + 3];     \
        a00 += (AQ).CMP * w0_; a01 += (AQ).CMP * w1_;               \
        a02 += (AQ).CMP * w2_; a03 += (AQ).CMP * w3_;               \
        a10 += (BQ).CMP * w0_; a11 += (BQ).CMP * w1_;               \
        a12 += (BQ).CMP * w2_; a13 += (BQ).CMP * w3_;               \
    }
#define FMATAP(U0, U1, U2, U3, W0, W1, W2, W3, T)   \
    {                                               \
        const float* wt_ = wp + (T) * (C * 4);      \
        CIW(U0, W0, x, 0) CIW(U0, W0, y, 1)         \
        CIW(U0, W0, z, 2) CIW(U0, W0, w, 3)         \
        CIW(U1, W1, x, 4) CIW(U1, W1, y, 5)         \
        CIW(U1, W1, z, 6) CIW(U1, W1, w, 7)         \
        CIW(U2, W2, x, 8) CIW(U2, W2, y, 9)         \
        CIW(U2, W2, z, 10) CIW(U2, W2, w, 11)       \
        CIW(U3, W3, x, 12) CIW(U3, W3, y, 13)       \
        CIW(U3, W3, z, 14) CIW(U3, W3, w, 15)       \
    }

template <int STRIDE, bool SPARSE>
__global__ __launch_bounds__(256) void conv_kernel(
    const float* __restrict__ in, float* __restrict__ out,
    const float* __restrict__ mask, const int* __restrict__ list,
    const int* __restrict__ nact, const float* __restrict__ Wq,
    const float* __restrict__ bs, const float* __restrict__ bb,
    int Din, int Dout) {
    int n = Dout * Dout * Dout;
    int nv = SPARSE ? *nact : n;
    if (SPARSE && nv > LISTCAP) nv = LISTCAP;
    if ((int)(blockIdx.x * 128) >= nv) return;  // uniform whole-block early exit

    int tid = threadIdx.x;
    int lane = tid & 63;
    int cq = __builtin_amdgcn_readfirstlane(tid >> 6);  // 0..3, wave-uniform
    const float* wp = Wq + cq * (TAPS * C * 4);         // 27 x 64 floats, scalar-rooted

    int s0 = blockIdx.x * 128 + lane * 2;
    int s1 = s0 + 1;
    bool val0 = s0 < nv, val1 = s1 < nv;
    int v0 = 0, v1 = 0;
    if (SPARSE) {
        if (val0) v0 = list[s0];
        if (val1) v1 = list[s1];
    } else {
        v0 = val0 ? s0 : 0;
        v1 = val1 ? s1 : 0;
    }
    int x0 = v0 % Dout, y0 = (v0 / Dout) % Dout, z0 = v0 / (Dout * Dout);
    int x1 = v1 % Dout, y1 = (v1 / Dout) % Dout, z1 = v1 / (Dout * Dout);
    float mk0 = SPARSE ? 1.f : (val0 ? mask[v0] : 0.f);
    float mk1 = SPARSE ? 1.f : (val1 ? mask[v1] : 0.f);

    float a00 = 0.f, a01 = 0.f, a02 = 0.f, a03 = 0.f;
    float a10 = 0.f, a11 = 0.f, a12 = 0.f, a13 = 0.f;

    const float4 z4 = make_float4(0.f, 0.f, 0.f, 0.f);
    auto taploads = [&](int t, float4& A0, float4& A1, float4& A2, float4& A3,
                        float4& B0, float4& B1, float4& B2, float4& B3) {
        int kz = cKZ[t], ky = cKY[t], kx = cKX[t];
        int zz0 = STRIDE * z0 - 1 + kz, yy0 = STRIDE * y0 - 1 + ky, xx0 = STRIDE * x0 - 1 + kx;
        int zz1 = STRIDE * z1 - 1 + kz, yy1 = STRIDE * y1 - 1 + ky, xx1 = STRIDE * x1 - 1 + kx;
        bool ok0 = ((unsigned)zz0 < (unsigned)Din) && ((unsigned)yy0 < (unsigned)Din) &&
                   ((unsigned)xx0 < (unsigned)Din);
        bool ok1 = ((unsigned)zz1 < (unsigned)Din) && ((unsigned)yy1 < (unsigned)Din) &&
                   ((unsigned)xx1 < (unsigned)Din);
        if (ok0) {
            const float4* p =
                reinterpret_cast<const float4*>(in + (long)((zz0 * Din + yy0) * Din + xx0) * C);
            A0 = p[0]; A1 = p[1]; A2 = p[2]; A3 = p[3];
        } else {
            A0 = z4; A1 = z4; A2 = z4; A3 = z4;
        }
        if (ok1) {
            const float4* p =
                reinterpret_cast<const float4*>(in + (long)((zz1 * Din + yy1) * Din + xx1) * C);
            B0 = p[0]; B1 = p[1]; B2 = p[2]; B3 = p[3];
        } else {
            B0 = z4; B1 = z4; B2 = z4; B3 = z4;
        }
    };

    float4 P0, P1, P2, P3, P4, P5, P6, P7;  // tap t
    float4 Q0, Q1, Q2, Q3, Q4, Q5, Q6, Q7;  // tap t+1
    taploads(0, P0, P1, P2, P3, P4, P5, P6, P7);
#pragma unroll 1
    for (int t = 0; t + 2 <= TAPS; t += 2) {
        taploads(t + 1, Q0, Q1, Q2, Q3, Q4, Q5, Q6, Q7);
        FMATAP(P0, P1, P2, P3, P4, P5, P6, P7, t)
        taploads(t + 2, P0, P1, P2, P3, P4, P5, P6, P7);  // t+2 <= 26: tap 26 valid
        FMATAP(Q0, Q1, Q2, Q3, Q4, Q5, Q6, Q7, t + 1)
    }
    FMATAP(P0, P1, P2, P3, P4, P5, P6, P7, TAPS - 1)  // tap 26

    int cob = cq * 4;
    float sc0 = bs[cob + 0], sc1 = bs[cob + 1], sc2 = bs[cob + 2], sc3 = bs[cob + 3];
    float bi0 = bb[cob + 0], bi1 = bb[cob + 1], bi2 = bb[cob + 2], bi3 = bb[cob + 3];
    if (val0) {
        float4* o4 = reinterpret_cast<float4*>(out + (long)v0 * C + cob);
        *o4 = make_float4(fmaxf(a00 * sc0 + bi0, 0.f) * mk0, fmaxf(a01 * sc1 + bi1, 0.f) * mk0,
                          fmaxf(a02 * sc2 + bi2, 0.f) * mk0, fmaxf(a03 * sc3 + bi3, 0.f) * mk0);
    }
    if (val1) {
        float4* o4 = reinterpret_cast<float4*>(out + (long)v1 * C + cob);
        *o4 = make_float4(fmaxf(a10 * sc0 + bi0, 0.f) * mk1, fmaxf(a11 * sc1 + bi1, 0.f) * mk1,
                          fmaxf(a12 * sc2 + bi2, 0.f) * mk1, fmaxf(a13 * sc3 + bi3, 0.f) * mk1);
    }
}

extern "C" void kernel_launch(void* const* d_in, const int* in_sizes, int n_in,
                              void* d_out, int out_size, void* d_ws, size_t ws_size,
                              hipStream_t stream) {
    const float* x = (const float*)d_in[0];
    const int* mask_idx = (const int*)d_in[1];
    const float* W = (const float*)d_in[2];
    const float* bs = (const float*)d_in[3];
    const float* bb = (const float*)d_in[4];
    float* out = (float*)d_out;
    float* ws = (float*)d_ws;

    const int n96 = 96 * 96 * 96;  // 884736
    const int n48 = 48 * 48 * 48;  // 110592
    const int n24 = 24 * 24 * 24;  // 13824
    const int n12 = 12 * 12 * 12;  // 1728
    const int n6 = 6 * 6 * 6;      // 216
    const int NB = (n96 + 255) / 256;  // 3456

    float* P0 = ws;                  // xt, then ping-pong
    float* P1 = P0 + (long)C * n96;  // ping-pong (pre-zeroed for sparse scatter)
    float* m48 = P1 + (long)C * n96;
    float* m24 = m48 + n48;
    float* m12 = m24 + n24;
    float* m6 = m12 + n12;
    float* Wq = m6 + n6;             // [l][4][27][16][4]
    int* list = (int*)(Wq + (long)NCONV * 4 * TAPS * C * 4);
    int* counts = list + LISTCAP;
    int* offsets = counts + NB;
    int* nact = offsets + NB;

    const int BS = 256;
    auto blk = [&](long t) { return dim3((unsigned)((t + BS - 1) / BS)); };
    auto cblk = [&](long nvox) { return dim3((unsigned)((nvox + 127) / 128)); };

    hipMemsetAsync(P1, 0, (long)C * n96 * sizeof(float), stream);
    hipLaunchKernelGGL(wq_kernel, blk(NCONV * 4 * TAPS * C * 4), dim3(BS), 0, stream, W, Wq);
    hipLaunchKernelGGL(transpose_in_kernel, blk(n96), dim3(BS), 0, stream, x, P0, n96);
    hipLaunchKernelGGL(count_kernel, dim3(NB), dim3(BS), 0, stream, mask_idx, counts, n96);
    hipLaunchKernelGGL(scan_kernel, dim3(1), dim3(BS), 0, stream, counts, offsets, nact, NB);
    hipLaunchKernelGGL(scatter_kernel, dim3(NB), dim3(BS), 0, stream, mask_idx, offsets, list,
                       n96, LISTCAP);

    auto sconv = [&](const float* in, float* op, int layer) {
        hipLaunchKernelGGL((conv_kernel<1, true>), cblk(LISTCAP), dim3(BS), 0, stream,
                           in, op, (const float*)nullptr, list, nact,
                           Wq + (long)layer * 4 * TAPS * C * 4, bs + layer * C, bb + layer * C,
                           96, 96);
    };
    auto subm = [&](const float* in, float* op, const float* m, int layer, int D) {
        int n = D * D * D;
        hipLaunchKernelGGL((conv_kernel<1, false>), cblk(n), dim3(BS), 0, stream,
                           in, op, m, list, nact, Wq + (long)layer * 4 * TAPS * C * 4,
                           bs + layer * C, bb + layer * C, D, D);
    };
    auto down = [&](const float* in, float* op, const float* m, int layer, int Dout) {
        int n = Dout * Dout * Dout;
        hipLaunchKernelGGL((conv_kernel<2, false>), cblk(n), dim3(BS), 0, stream,
                           in, op, m, list, nact, Wq + (long)layer * 4 * TAPS * C * 4,
                           bs + layer * C, bb + layer * C, 2 * Dout, Dout);
    };

    // masks
    hipLaunchKernelGGL((pool_mask_kernel<true>), blk(n48), dim3(BS), 0, stream,
                       mask_idx, (const float*)nullptr, m48, 96, 48);
    hipLaunchKernelGGL((pool_mask_kernel<false>), blk(n24), dim3(BS), 0, stream,
                       (const int*)nullptr, m48, m24, 48, 24);
    hipLaunchKernelGGL((pool_mask_kernel<false>), blk(n12), dim3(BS), 0, stream,
                       (const int*)nullptr, m24, m12, 24, 12);
    hipLaunchKernelGGL((pool_mask_kernel<false>), blk(n6), dim3(BS), 0, stream,
                       (const int*)nullptr, m12, m6, 12, 6);

    // Stage @96 (sparse). L0: P0(xt) -> P1 (zeroed). L1: P1 -> P0 (inactive already 0 from x*mask).
    sconv(P0, P1, 0);
    sconv(P1, P0, 1);
    // 48 level (dense, ~94% mask)
    down(P0, P1, m48, 2, 48);
    subm(P1, P0, m48, 3, 48);
    subm(P0, P1, m48, 4, 48);  // net1 in P1
    hipLaunchKernelGGL(to_ncdhw_kernel, blk(n48), dim3(BS), 0, stream, P1, out, n48);
    // 24 level
    down(P1, P0, m24, 5, 24);
    subm(P0, P1, m24, 6, 24);
    subm(P1, P0, m24, 7, 24);
    subm(P0, P1, m24, 8, 24);  // net2 in P1
    hipLaunchKernelGGL(to_ncdhw_kernel, blk(n24), dim3(BS), 0, stream, P1, out + (long)C * n48, n24);
    // 12 level
    down(P1, P0, m12, 9, 12);
    subm(P0, P1, m12, 10, 12);
    subm(P1, P0, m12, 11, 12);
    subm(P0, P1, m12, 12, 12);  // net3 in P1
    hipLaunchKernelGGL(to_ncdhw_kernel, blk(n12), dim3(BS), 0, stream, P1,
                       out + (long)C * (n48 + n24), n12);
    // 6 level
    down(P1, P0, m6, 13, 6);
    subm(P0, P1, m6, 14, 6);
    subm(P1, P0, m6, 15, 6);
    subm(P0, P1, m6, 16, 6);  // net4 in P1
    hipLaunchKernelGGL(to_ncdhw_kernel, blk(n6), dim3(BS), 0, stream, P1,
                       out + (long)C * (n48 + n24 + n12), n6);
}

// Round 12
// 709.330 us; speedup vs baseline: 1.4364x; 1.4364x over previous
//
#include <hip/hip_runtime.h>

#define C 16
#define TAPS 27
#define NCONV 17
#define LISTCAP 98304   // >> expected ~88.5K actives

// ---- weight prep: W[l][co][ci][tap] -> Wq[l][cq][tap][ci][4]  (co = cq*4+j) ----
__global__ void wq_kernel(const float* __restrict__ W, float* __restrict__ Wq) {
    int i = blockIdx.x * blockDim.x + threadIdx.x;
    const int total = NCONV * 4 * TAPS * C * 4;
    if (i >= total) return;
    int j = i & 3;
    int ci = (i >> 2) & 15;
    int t = (i >> 6) % TAPS;
    int rest = (i >> 6) / TAPS;
    int cq = rest & 3;
    int l = rest >> 2;
    int co = cq * 4 + j;
    Wq[i] = W[(((l * C + co) * C + ci) * TAPS) + t];
}

// ---- x: NCDHW -> NDHWC ----
__global__ void transpose_in_kernel(const float* __restrict__ x, float* __restrict__ xt, int n) {
    int v = blockIdx.x * blockDim.x + threadIdx.x;
    if (v >= n) return;
    float a[C];
#pragma unroll
    for (int ci = 0; ci < C; ci++) a[ci] = x[(long)ci * n + v];
    float4* dp = reinterpret_cast<float4*>(xt + (long)v * C);
    dp[0] = make_float4(a[0], a[1], a[2], a[3]);
    dp[1] = make_float4(a[4], a[5], a[6], a[7]);
    dp[2] = make_float4(a[8], a[9], a[10], a[11]);
    dp[3] = make_float4(a[12], a[13], a[14], a[15]);
}

// ---- NDHWC -> NCDHW (stage outputs into d_out) ----
__global__ void to_ncdhw_kernel(const float* __restrict__ src, float* __restrict__ dst, int n) {
    int v = blockIdx.x * blockDim.x + threadIdx.x;
    if (v >= n) return;
    const float4* sp = reinterpret_cast<const float4*>(src + (long)v * C);
    float4 q0 = sp[0], q1 = sp[1], q2 = sp[2], q3 = sp[3];
    dst[0L * n + v] = q0.x;  dst[1L * n + v] = q0.y;
    dst[2L * n + v] = q0.z;  dst[3L * n + v] = q0.w;
    dst[4L * n + v] = q1.x;  dst[5L * n + v] = q1.y;
    dst[6L * n + v] = q1.z;  dst[7L * n + v] = q1.w;
    dst[8L * n + v] = q2.x;  dst[9L * n + v] = q2.y;
    dst[10L * n + v] = q2.z; dst[11L * n + v] = q2.w;
    dst[12L * n + v] = q3.x; dst[13L * n + v] = q3.y;
    dst[14L * n + v] = q3.z; dst[15L * n + v] = q3.w;
}

// ---- ordered compaction: counts -> scan -> scatter ----
__global__ void count_kernel(const int* __restrict__ mi, int* __restrict__ counts, int n) {
    int i = blockIdx.x * 256 + threadIdx.x;
    int act = (i < n) && (mi[i] == 0);
    unsigned long long b = __ballot(act);
    __shared__ int wsum[4];
    int wid = threadIdx.x >> 6, lane = threadIdx.x & 63;
    if (lane == 0) wsum[wid] = __popcll(b);
    __syncthreads();
    if (threadIdx.x == 0) counts[blockIdx.x] = wsum[0] + wsum[1] + wsum[2] + wsum[3];
}

__global__ void scan_kernel(const int* __restrict__ counts, int* __restrict__ offsets,
                            int* __restrict__ nact, int nb) {
    __shared__ int s[256];
    int t = threadIdx.x;
    const int CH = (nb + 255) / 256;
    int base = t * CH, sum = 0;
    for (int j = 0; j < CH; j++)
        if (base + j < nb) sum += counts[base + j];
    s[t] = sum;
    __syncthreads();
    for (int off = 1; off < 256; off <<= 1) {
        int v = (t >= off) ? s[t - off] : 0;
        __syncthreads();
        s[t] += v;
        __syncthreads();
    }
    int run = s[t] - sum;  // exclusive base
    for (int j = 0; j < CH; j++) {
        if (base + j < nb) {
            offsets[base + j] = run;
            run += counts[base + j];
        }
    }
    if (t == 255) *nact = s[255];
}

__global__ void scatter_kernel(const int* __restrict__ mi, const int* __restrict__ offsets,
                               int* __restrict__ list, int n, int cap) {
    int i = blockIdx.x * 256 + threadIdx.x;
    int act = (i < n) && (mi[i] == 0);
    unsigned long long b = __ballot(act);
    __shared__ int wsum[4];
    int wid = threadIdx.x >> 6, lane = threadIdx.x & 63;
    if (lane == 0) wsum[wid] = __popcll(b);
    __syncthreads();
    int wbase = 0;
    for (int w = 0; w < wid; w++) wbase += wsum[w];
    int prefix = __popcll(b & ((1ull << lane) - 1));
    if (act) {
        int pos = offsets[blockIdx.x] + wbase + prefix;
        if (pos < cap) list[pos] = i;
    }
}

// ---- mask maxpool (2x2x2 stride, 3^3 window) ----
template <bool FROM_INT>
__global__ void pool_mask_kernel(const int* __restrict__ mi, const float* __restrict__ mf,
                                 float* __restrict__ mout, int Din, int Dout) {
    int i = blockIdx.x * blockDim.x + threadIdx.x;
    int n = Dout * Dout * Dout;
    if (i >= n) return;
    int x = i % Dout, y = (i / Dout) % Dout, z = i / (Dout * Dout);
    float v = 0.f;
    for (int kz = 0; kz < 3; kz++) {
        int zz = 2 * z - 1 + kz;
        if (zz < 0 || zz >= Din) continue;
        for (int ky = 0; ky < 3; ky++) {
            int yy = 2 * y - 1 + ky;
            if (yy < 0 || yy >= Din) continue;
            for (int kx = 0; kx < 3; kx++) {
                int xx = 2 * x - 1 + kx;
                if (xx < 0 || xx >= Din) continue;
                long idx = ((long)zz * Din + yy) * Din + xx;
                float mv = FROM_INT ? ((mi[idx] == 0) ? 1.f : 0.f) : mf[idx];
                v = fmaxf(v, mv);
            }
        }
    }
    mout[i] = v;
}

// ---- conv in NDHWC: block = 64 voxels x 4 co-quad waves (256 thr) ----
// lane = voxel (64/block), wave = co-quad -> 5.4 waves/SIMD at 100K voxels
// (r9-proven occupancy). Weights from LDS with WAVE-UNIFORM address
// (broadcast b128, r1-proven ~free): wl4[cq*432 + tap*16 + ci].
// Inputs: 4 float4/tap/lane (NDHWC), 2-deep tap prefetch (8 quads live,
// r7-proven no-spill). Accumulator: 4 named scalars.
#define CIW(AQ, CMP, CI)                                   \
    {                                                      \
        float4 w_ = wt_[(CI)];                             \
        a0 += (AQ).CMP * w_.x; a1 += (AQ).CMP * w_.y;      \
        a2 += (AQ).CMP * w_.z; a3 += (AQ).CMP * w_.w;      \
    }
#define FMATAP(U0, U1, U2, U3, T)                  \
    {                                              \
        const float4* wt_ = wbase + ((T) << 4);    \
        CIW(U0, x, 0) CIW(U0, y, 1)                \
        CIW(U0, z, 2) CIW(U0, w, 3)                \
        CIW(U1, x, 4) CIW(U1, y, 5)                \
        CIW(U1, z, 6) CIW(U1, w, 7)                \
        CIW(U2, x, 8) CIW(U2, y, 9)                \
        CIW(U2, z, 10) CIW(U2, w, 11)              \
        CIW(U3, x, 12) CIW(U3, y, 13)              \
        CIW(U3, z, 14) CIW(U3, w, 15)              \
    }

template <int STRIDE, bool SPARSE>
__global__ __launch_bounds__(256) void conv_kernel(
    const float* __restrict__ in, float* __restrict__ out,
    const float* __restrict__ mask, const int* __restrict__ list,
    const int* __restrict__ nact, const float* __restrict__ Wq,
    const float* __restrict__ bs, const float* __restrict__ bb,
    int Din, int Dout) {
    int n = Dout * Dout * Dout;
    int nv = SPARSE ? *nact : n;
    if (SPARSE && nv > LISTCAP) nv = LISTCAP;
    if ((int)(blockIdx.x * 64) >= nv) return;  // uniform whole-block early exit

    __shared__ float4 wl4[4 * TAPS * C];  // [cq][tap][ci] as float4 = 27.6KB
    int tid = threadIdx.x;
    {
        const float4* ws4 = reinterpret_cast<const float4*>(Wq);
        for (int idx = tid; idx < 4 * TAPS * C; idx += 256) wl4[idx] = ws4[idx];
    }
    __syncthreads();

    int lane = tid & 63;
    int cq = __builtin_amdgcn_readfirstlane(tid >> 6);  // 0..3, wave-uniform
    const float4* wbase = wl4 + cq * (TAPS * C);

    int s0 = blockIdx.x * 64 + lane;
    bool val = s0 < nv;
    int v = 0;
    if (SPARSE) {
        if (val) v = list[s0];
    } else {
        v = val ? s0 : 0;
    }
    int x = v % Dout, y = (v / Dout) % Dout, z = v / (Dout * Dout);
    float mk = SPARSE ? 1.f : (val ? mask[v] : 0.f);

    float a0 = 0.f, a1 = 0.f, a2 = 0.f, a3 = 0.f;

    const float4 z4 = make_float4(0.f, 0.f, 0.f, 0.f);
    auto taploads = [&](int t, float4& T0, float4& T1, float4& T2, float4& T3) {
        int kz = t / 9;
        int r = t - kz * 9;
        int ky = r / 3;
        int kx = r - ky * 3;
        int zz = STRIDE * z - 1 + kz;
        int yy = STRIDE * y - 1 + ky;
        int xx = STRIDE * x - 1 + kx;
        bool ok = ((unsigned)zz < (unsigned)Din) && ((unsigned)yy < (unsigned)Din) &&
                  ((unsigned)xx < (unsigned)Din);
        if (ok) {
            const float4* p =
                reinterpret_cast<const float4*>(in + (long)((zz * Din + yy) * Din + xx) * C);
            T0 = p[0]; T1 = p[1]; T2 = p[2]; T3 = p[3];
        } else {
            T0 = z4; T1 = z4; T2 = z4; T3 = z4;
        }
    };

    float4 P0, P1, P2, P3, Q0, Q1, Q2, Q3;
    taploads(0, P0, P1, P2, P3);
#pragma unroll 1
    for (int t = 0; t + 2 <= TAPS; t += 2) {
        taploads(t + 1, Q0, Q1, Q2, Q3);
        FMATAP(P0, P1, P2, P3, t)
        taploads(t + 2, P0, P1, P2, P3);  // t+2 <= 26: tap 26 valid
        FMATAP(Q0, Q1, Q2, Q3, t + 1)
    }
    FMATAP(P0, P1, P2, P3, TAPS - 1)  // tap 26

    if (val) {
        int cob = cq * 4;
        float r0 = fmaxf(a0 * bs[cob + 0] + bb[cob + 0], 0.f) * mk;
        float r1 = fmaxf(a1 * bs[cob + 1] + bb[cob + 1], 0.f) * mk;
        float r2 = fmaxf(a2 * bs[cob + 2] + bb[cob + 2], 0.f) * mk;
        float r3 = fmaxf(a3 * bs[cob + 3] + bb[cob + 3], 0.f) * mk;
        float4* o4 = reinterpret_cast<float4*>(out + (long)v * C + cob);
        *o4 = make_float4(r0, r1, r2, r3);
    }
}

extern "C" void kernel_launch(void* const* d_in, const int* in_sizes, int n_in,
                              void* d_out, int out_size, void* d_ws, size_t ws_size,
                              hipStream_t stream) {
    const float* x = (const float*)d_in[0];
    const int* mask_idx = (const int*)d_in[1];
    const float* W = (const float*)d_in[2];
    const float* bs = (const float*)d_in[3];
    const float* bb = (const float*)d_in[4];
    float* out = (float*)d_out;
    float* ws = (float*)d_ws;

    const int n96 = 96 * 96 * 96;  // 884736
    const int n48 = 48 * 48 * 48;  // 110592
    const int n24 = 24 * 24 * 24;  // 13824
    const int n12 = 12 * 12 * 12;  // 1728
    const int n6 = 6 * 6 * 6;      // 216
    const int NB = (n96 + 255) / 256;  // 3456

    float* P0 = ws;                  // xt, then ping-pong
    float* P1 = P0 + (long)C * n96;  // ping-pong (pre-zeroed for sparse scatter)
    float* m48 = P1 + (long)C * n96;
    float* m24 = m48 + n48;
    float* m12 = m24 + n24;
    float* m6 = m12 + n12;
    float* Wq = m6 + n6;             // [l][cq][tap][ci][4]
    int* list = (int*)(Wq + (long)NCONV * 4 * TAPS * C * 4);
    int* counts = list + LISTCAP;
    int* offsets = counts + NB;
    int* nact = offsets + NB;

    const int BS = 256;
    auto blk = [&](long t) { return dim3((unsigned)((t + BS - 1) / BS)); };
    auto cblk = [&](long nvox) { return dim3((unsigned)((nvox + 63) / 64)); };

    hipMemsetAsync(P1, 0, (long)C * n96 * sizeof(float), stream);
    hipLaunchKernelGGL(wq_kernel, blk(NCONV * 4 * TAPS * C * 4), dim3(BS), 0, stream, W, Wq);
    hipLaunchKernelGGL(transpose_in_kernel, blk(n96), dim3(BS), 0, stream, x, P0, n96);
    hipLaunchKernelGGL(count_kernel, dim3(NB), dim3(BS), 0, stream, mask_idx, counts, n96);
    hipLaunchKernelGGL(scan_kernel, dim3(1), dim3(BS), 0, stream, counts, offsets, nact, NB);
    hipLaunchKernelGGL(scatter_kernel, dim3(NB), dim3(BS), 0, stream, mask_idx, offsets, list,
                       n96, LISTCAP);

    auto sconv = [&](const float* in, float* op, int layer) {
        hipLaunchKernelGGL((conv_kernel<1, true>), cblk(LISTCAP), dim3(BS), 0, stream,
                           in, op, (const float*)nullptr, list, nact,
                           Wq + (long)layer * 4 * TAPS * C * 4, bs + layer * C, bb + layer * C,
                           96, 96);
    };
    auto subm = [&](const float* in, float* op, const float* m, int layer, int D) {
        int n = D * D * D;
        hipLaunchKernelGGL((conv_kernel<1, false>), cblk(n), dim3(BS), 0, stream,
                           in, op, m, list, nact, Wq + (long)layer * 4 * TAPS * C * 4,
                           bs + layer * C, bb + layer * C, D, D);
    };
    auto down = [&](const float* in, float* op, const float* m, int layer, int Dout) {
        int n = Dout * Dout * Dout;
        hipLaunchKernelGGL((conv_kernel<2, false>), cblk(n), dim3(BS), 0, stream,
                           in, op, m, list, nact, Wq + (long)layer * 4 * TAPS * C * 4,
                           bs + layer * C, bb + layer * C, 2 * Dout, Dout);
    };

    // masks
    hipLaunchKernelGGL((pool_mask_kernel<true>), blk(n48), dim3(BS), 0, stream,
                       mask_idx, (const float*)nullptr, m48, 96, 48);
    hipLaunchKernelGGL((pool_mask_kernel<false>), blk(n24), dim3(BS), 0, stream,
                       (const int*)nullptr, m48, m24, 48, 24);
    hipLaunchKernelGGL((pool_mask_kernel<false>), blk(n12), dim3(BS), 0, stream,
                       (const int*)nullptr, m24, m12, 24, 12);
    hipLaunchKernelGGL((pool_mask_kernel<false>), blk(n6), dim3(BS), 0, stream,
                       (const int*)nullptr, m12, m6, 12, 6);

    // Stage @96 (sparse). L0: P0(xt) -> P1 (zeroed). L1: P1 -> P0 (inactive already 0 from x*mask).
    sconv(P0, P1, 0);
    sconv(P1, P0, 1);
    // 48 level (dense, ~94% mask)
    down(P0, P1, m48, 2, 48);
    subm(P1, P0, m48, 3, 48);
    subm(P0, P1, m48, 4, 48);  // net1 in P1
    hipLaunchKernelGGL(to_ncdhw_kernel, blk(n48), dim3(BS), 0, stream, P1, out, n48);
    // 24 level
    down(P1, P0, m24, 5, 24);
    subm(P0, P1, m24, 6, 24);
    subm(P1, P0, m24, 7, 24);
    subm(P0, P1, m24, 8, 24);  // net2 in P1
    hipLaunchKernelGGL(to_ncdhw_kernel, blk(n24), dim3(BS), 0, stream, P1, out + (long)C * n48, n24);
    // 12 level
    down(P1, P0, m12, 9, 12);
    subm(P0, P1, m12, 10, 12);
    subm(P1, P0, m12, 11, 12);
    subm(P0, P1, m12, 12, 12);  // net3 in P1
    hipLaunchKernelGGL(to_ncdhw_kernel, blk(n12), dim3(BS), 0, stream, P1,
                       out + (long)C * (n48 + n24), n12);
    // 6 level
    down(P1, P0, m6, 13, 6);
    subm(P0, P1, m6, 14, 6);
    subm(P1, P0, m6, 15, 6);
    subm(P0, P1, m6, 16, 6);  // net4 in P1
    hipLaunchKernelGGL(to_ncdhw_kernel, blk(n6), dim3(BS), 0, stream, P1,
                       out + (long)C * (n48 + n24 + n12), n6);
}

// Round 13
// 226.833 us; speedup vs baseline: 4.4918x; 3.1271x over previous
//
#include <hip/hip_runtime.h>

#define C 16
#define TAPS 27
#define NCONV 17
#define LISTCAP 98304
#define NPAIR 14

typedef _Float16 half8 __attribute__((ext_vector_type(8)));
typedef _Float16 half4 __attribute__((ext_vector_type(4)));
typedef float f32x4 __attribute__((ext_vector_type(4)));

// ---- weight prep: W[l][co][ci][tap] -> Wh[l][pair][lane][8] fp16 (MFMA A-frag) ----
// lane: co = lane&15 (M row), g = lane>>4; k = 8g+j; ci = k&15; tap = 2p + (k>>4).
__global__ void wh_kernel(const float* __restrict__ W, _Float16* __restrict__ Wh) {
    int i = blockIdx.x * blockDim.x + threadIdx.x;
    const int total = NCONV * NPAIR * 64 * 8;
    if (i >= total) return;
    int j = i & 7;
    int lane = (i >> 3) & 63;
    int p = (i >> 9) % NPAIR;
    int l = (i >> 9) / NPAIR;
    int co = lane & 15;
    int g = lane >> 4;
    int k = 8 * g + j;
    int ci = k & 15;
    int tap = 2 * p + (k >> 4);
    float val = (tap < TAPS) ? W[((l * C + co) * C + ci) * TAPS + tap] : 0.f;
    Wh[i] = (_Float16)val;
}

// ---- x: NCDHW fp32 -> NDHWC fp16 ----
__global__ void transpose_in_h(const float* __restrict__ x, _Float16* __restrict__ xt, int n) {
    int v = blockIdx.x * blockDim.x + threadIdx.x;
    if (v >= n) return;
    half8 h0, h1;
#pragma unroll
    for (int c = 0; c < 8; c++) h0[c] = (_Float16)x[(long)c * n + v];
#pragma unroll
    for (int c = 0; c < 8; c++) h1[c] = (_Float16)x[(long)(c + 8) * n + v];
    half8* dp = reinterpret_cast<half8*>(xt + (long)v * C);
    dp[0] = h0;
    dp[1] = h1;
}

// ---- NDHWC fp16 -> NCDHW fp32 (stage outputs into d_out) ----
__global__ void to_ncdhw_h(const _Float16* __restrict__ src, float* __restrict__ dst, int n) {
    int v = blockIdx.x * blockDim.x + threadIdx.x;
    if (v >= n) return;
    const half8* sp = reinterpret_cast<const half8*>(src + (long)v * C);
    half8 q0 = sp[0], q1 = sp[1];
#pragma unroll
    for (int c = 0; c < 8; c++) dst[(long)c * n + v] = (float)q0[c];
#pragma unroll
    for (int c = 0; c < 8; c++) dst[(long)(c + 8) * n + v] = (float)q1[c];
}

// ---- ordered compaction: counts -> scan -> scatter ----
__global__ void count_kernel(const int* __restrict__ mi, int* __restrict__ counts, int n) {
    int i = blockIdx.x * 256 + threadIdx.x;
    int act = (i < n) && (mi[i] == 0);
    unsigned long long b = __ballot(act);
    __shared__ int wsum[4];
    int wid = threadIdx.x >> 6, lane = threadIdx.x & 63;
    if (lane == 0) wsum[wid] = __popcll(b);
    __syncthreads();
    if (threadIdx.x == 0) counts[blockIdx.x] = wsum[0] + wsum[1] + wsum[2] + wsum[3];
}

__global__ void scan_kernel(const int* __restrict__ counts, int* __restrict__ offsets,
                            int* __restrict__ nact, int nb) {
    __shared__ int s[256];
    int t = threadIdx.x;
    const int CH = (nb + 255) / 256;
    int base = t * CH, sum = 0;
    for (int j = 0; j < CH; j++)
        if (base + j < nb) sum += counts[base + j];
    s[t] = sum;
    __syncthreads();
    for (int off = 1; off < 256; off <<= 1) {
        int v = (t >= off) ? s[t - off] : 0;
        __syncthreads();
        s[t] += v;
        __syncthreads();
    }
    int run = s[t] - sum;  // exclusive base
    for (int j = 0; j < CH; j++) {
        if (base + j < nb) {
            offsets[base + j] = run;
            run += counts[base + j];
        }
    }
    if (t == 255) *nact = s[255];
}

__global__ void scatter_kernel(const int* __restrict__ mi, const int* __restrict__ offsets,
                               int* __restrict__ list, int n, int cap) {
    int i = blockIdx.x * 256 + threadIdx.x;
    int act = (i < n) && (mi[i] == 0);
    unsigned long long b = __ballot(act);
    __shared__ int wsum[4];
    int wid = threadIdx.x >> 6, lane = threadIdx.x & 63;
    if (lane == 0) wsum[wid] = __popcll(b);
    __syncthreads();
    int wbase = 0;
    for (int w = 0; w < wid; w++) wbase += wsum[w];
    int prefix = __popcll(b & ((1ull << lane) - 1));
    if (act) {
        int pos = offsets[blockIdx.x] + wbase + prefix;
        if (pos < cap) list[pos] = i;
    }
}

// ---- mask maxpool (2x2x2 stride, 3^3 window) ----
template <bool FROM_INT>
__global__ void pool_mask_kernel(const int* __restrict__ mi, const float* __restrict__ mf,
                                 float* __restrict__ mout, int Din, int Dout) {
    int i = blockIdx.x * blockDim.x + threadIdx.x;
    int n = Dout * Dout * Dout;
    if (i >= n) return;
    int x = i % Dout, y = (i / Dout) % Dout, z = i / (Dout * Dout);
    float v = 0.f;
    for (int kz = 0; kz < 3; kz++) {
        int zz = 2 * z - 1 + kz;
        if (zz < 0 || zz >= Din) continue;
        for (int ky = 0; ky < 3; ky++) {
            int yy = 2 * y - 1 + ky;
            if (yy < 0 || yy >= Din) continue;
            for (int kx = 0; kx < 3; kx++) {
                int xx = 2 * x - 1 + kx;
                if (xx < 0 || xx >= Din) continue;
                long idx = ((long)zz * Din + yy) * Din + xx;
                float mv = FROM_INT ? ((mi[idx] == 0) ? 1.f : 0.f) : mf[idx];
                v = fmaxf(v, mv);
            }
        }
    }
    mout[i] = v;
}

// ---- MFMA conv: one wave = one 16-voxel tile, D = W(16co x 32k) * Act(32k x 16vox) ----
// A (weights): resident, 14 pairs x 4 VGPR. Lane: co=lane&15, k-chunk g=lane>>4.
// B (activations): per pair ONE 16B load/lane: voxel (lane&15), tap 2p+(g>>1),
//   ci offset (g&1)*8, from NDHWC fp16. OOB or invalid -> 0.
// D: col=lane&15=voxel, row=4g+reg=co (HW-verified C/D layout).
template <int STRIDE, bool SPARSE>
__global__ __launch_bounds__(256) void mconv_kernel(
    const _Float16* __restrict__ in, _Float16* __restrict__ out,
    const float* __restrict__ mask, const int* __restrict__ list,
    const int* __restrict__ nact, const _Float16* __restrict__ Whl,
    const float* __restrict__ bs, const float* __restrict__ bb,
    int Din, int Dout) {
    int n = Dout * Dout * Dout;
    int nv;
    if (SPARSE) {
        nv = *nact;
        if (nv > LISTCAP) nv = LISTCAP;
    } else {
        nv = n;
    }
    int tile = blockIdx.x * 4 + (threadIdx.x >> 6);
    if (tile * 16 >= nv) return;  // per-wave exit (no barriers in kernel)

    int lane = threadIdx.x & 63;
    int col = lane & 15;  // voxel slot
    int g = lane >> 4;    // k-chunk group
    int s = tile * 16 + col;
    bool val = s < nv;
    int v = 0;
    if (SPARSE) {
        if (val) v = list[s];
    } else {
        v = val ? s : 0;
    }
    int x = v % Dout, y = (v / Dout) % Dout, z = v / (Dout * Dout);

    // resident A fragments
    const half8* wf = reinterpret_cast<const half8*>(Whl);
    half8 a[NPAIR];
#pragma unroll
    for (int p = 0; p < NPAIR; p++) a[p] = wf[p * 64 + lane];

    int half_off = (g & 1) * 8;  // ci offset within tap
    int tg = g >> 1;             // which tap of the pair

    f32x4 acc = {0.f, 0.f, 0.f, 0.f};
#pragma unroll
    for (int p = 0; p < NPAIR; p++) {
        int tap = 2 * p + tg;
        if (tap > TAPS - 1) tap = TAPS - 1;  // dummy half: weights are 0
        int kz = tap / 9, ky = (tap / 3) % 3, kx = tap % 3;
        int zz = STRIDE * z - 1 + kz;
        int yy = STRIDE * y - 1 + ky;
        int xx = STRIDE * x - 1 + kx;
        bool ok = val && ((unsigned)zz < (unsigned)Din) && ((unsigned)yy < (unsigned)Din) &&
                  ((unsigned)xx < (unsigned)Din);
        half8 b = {};
        if (ok) {
            b = *reinterpret_cast<const half8*>(
                in + (long)((zz * Din + yy) * Din + xx) * C + half_off);
        }
        acc = __builtin_amdgcn_mfma_f32_16x16x32_f16(a[p], b, acc, 0, 0, 0);
    }

    if (val) {
        float mk = SPARSE ? 1.f : mask[v];
        int cob = g * 4;
        half4 r;
#pragma unroll
        for (int j = 0; j < 4; j++) {
            float t = fmaxf(acc[j] * bs[cob + j] + bb[cob + j], 0.f) * mk;
            r[j] = (_Float16)t;
        }
        *reinterpret_cast<half4*>(out + (long)v * C + cob) = r;
    }
}

extern "C" void kernel_launch(void* const* d_in, const int* in_sizes, int n_in,
                              void* d_out, int out_size, void* d_ws, size_t ws_size,
                              hipStream_t stream) {
    const float* x = (const float*)d_in[0];
    const int* mask_idx = (const int*)d_in[1];
    const float* W = (const float*)d_in[2];
    const float* bs = (const float*)d_in[3];
    const float* bb = (const float*)d_in[4];
    float* out = (float*)d_out;

    const int n96 = 96 * 96 * 96;  // 884736
    const int n48 = 48 * 48 * 48;  // 110592
    const int n24 = 24 * 24 * 24;  // 13824
    const int n12 = 12 * 12 * 12;  // 1728
    const int n6 = 6 * 6 * 6;      // 216
    const int NB = (n96 + 255) / 256;  // 3456

    _Float16* P0h = (_Float16*)d_ws;
    _Float16* P1h = P0h + (long)C * n96;
    float* m48 = (float*)(P1h + (long)C * n96);
    float* m24 = m48 + n48;
    float* m12 = m24 + n24;
    float* m6 = m12 + n12;
    _Float16* Wh = (_Float16*)(m6 + n6);  // [l][14][64][8]
    int* list = (int*)(Wh + (long)NCONV * NPAIR * 64 * 8);
    int* counts = list + LISTCAP;
    int* offsets = counts + NB;
    int* nact = offsets + NB;

    const int BS = 256;
    auto blk = [&](long t) { return dim3((unsigned)((t + BS - 1) / BS)); };
    // one wave per 16-voxel tile, 4 waves per block
    auto mblk = [&](long nvox) { return dim3((unsigned)((nvox + 63) / 64)); };

    hipMemsetAsync(P1h, 0, (long)C * n96 * sizeof(_Float16), stream);
    hipLaunchKernelGGL(wh_kernel, blk(NCONV * NPAIR * 64 * 8), dim3(BS), 0, stream, W, Wh);
    hipLaunchKernelGGL(transpose_in_h, blk(n96), dim3(BS), 0, stream, x, P0h, n96);
    hipLaunchKernelGGL(count_kernel, dim3(NB), dim3(BS), 0, stream, mask_idx, counts, n96);
    hipLaunchKernelGGL(scan_kernel, dim3(1), dim3(BS), 0, stream, counts, offsets, nact, NB);
    hipLaunchKernelGGL(scatter_kernel, dim3(NB), dim3(BS), 0, stream, mask_idx, offsets, list,
                       n96, LISTCAP);

    auto sconv = [&](const _Float16* in, _Float16* op, int layer) {
        hipLaunchKernelGGL((mconv_kernel<1, true>), mblk(LISTCAP), dim3(BS), 0, stream,
                           in, op, (const float*)nullptr, list, nact,
                           Wh + (long)layer * NPAIR * 64 * 8, bs + layer * C, bb + layer * C,
                           96, 96);
    };
    auto subm = [&](const _Float16* in, _Float16* op, const float* m, int layer, int D) {
        int n = D * D * D;
        hipLaunchKernelGGL((mconv_kernel<1, false>), mblk(n), dim3(BS), 0, stream,
                           in, op, m, list, nact, Wh + (long)layer * NPAIR * 64 * 8,
                           bs + layer * C, bb + layer * C, D, D);
    };
    auto down = [&](const _Float16* in, _Float16* op, const float* m, int layer, int Dout) {
        int n = Dout * Dout * Dout;
        hipLaunchKernelGGL((mconv_kernel<2, false>), mblk(n), dim3(BS), 0, stream,
                           in, op, m, list, nact, Wh + (long)layer * NPAIR * 64 * 8,
                           bs + layer * C, bb + layer * C, 2 * Dout, Dout);
    };

    // masks
    hipLaunchKernelGGL((pool_mask_kernel<true>), blk(n48), dim3(BS), 0, stream,
                       mask_idx, (const float*)nullptr, m48, 96, 48);
    hipLaunchKernelGGL((pool_mask_kernel<false>), blk(n24), dim3(BS), 0, stream,
                       (const int*)nullptr, m48, m24, 48, 24);
    hipLaunchKernelGGL((pool_mask_kernel<false>), blk(n12), dim3(BS), 0, stream,
                       (const int*)nullptr, m24, m12, 24, 12);
    hipLaunchKernelGGL((pool_mask_kernel<false>), blk(n6), dim3(BS), 0, stream,
                       (const int*)nullptr, m12, m6, 12, 6);

    // Stage @96 (sparse). L0: P0h(xt) -> P1h (zeroed). L1: P1h -> P0h (inactive already 0).
    sconv(P0h, P1h, 0);
    sconv(P1h, P0h, 1);
    // 48 level (dense)
    down(P0h, P1h, m48, 2, 48);
    subm(P1h, P0h, m48, 3, 48);
    subm(P0h, P1h, m48, 4, 48);  // net1 in P1h
    hipLaunchKernelGGL(to_ncdhw_h, blk(n48), dim3(BS), 0, stream, P1h, out, n48);
    // 24 level
    down(P1h, P0h, m24, 5, 24);
    subm(P0h, P1h, m24, 6, 24);
    subm(P1h, P0h, m24, 7, 24);
    subm(P0h, P1h, m24, 8, 24);  // net2 in P1h
    hipLaunchKernelGGL(to_ncdhw_h, blk(n24), dim3(BS), 0, stream, P1h, out + (long)C * n48, n24);
    // 12 level
    down(P1h, P0h, m12, 9, 12);
    subm(P0h, P1h, m12, 10, 12);
    subm(P1h, P0h, m12, 11, 12);
    subm(P0h, P1h, m12, 12, 12);  // net3 in P1h
    hipLaunchKernelGGL(to_ncdhw_h, blk(n12), dim3(BS), 0, stream, P1h,
                       out + (long)C * (n48 + n24), n12);
    // 6 level
    down(P1h, P0h, m6, 13, 6);
    subm(P0h, P1h, m6, 14, 6);
    subm(P1h, P0h, m6, 15, 6);
    subm(P0h, P1h, m6, 16, 6);  // net4 in P1h
    hipLaunchKernelGGL(to_ncdhw_h, blk(n6), dim3(BS), 0, stream, P1h,
                       out + (long)C * (n48 + n24 + n12), n6);
}